// Round 17
// baseline (114.232 us; speedup 1.0000x reference)
//
#include <hip/hip_runtime.h>
#include <hip/hip_cooperative_groups.h>
#include <hip/hip_bf16.h>
#include <math.h>

namespace cg = cooperative_groups;

// Problem constants
#define B_    16
#define C_    256
#define L_    64
#define N_    8192
#define HEAD_ 8
#define HC_   32        // C/HEAD
#define M_    12

#define SQRT32F 5.656854249492380f
#define PI_F    3.14159265358979323846f
#define BN_INV  0.99999500003749969f     // 1/sqrt(1+1e-5)

typedef float v4f __attribute__((ext_vector_type(4)));

// ---------------------------------------------------------------------------
// ONE cooperative kernel. 256 blocks x 512 threads, 1 block/CU (103 KB LDS).
//  phase A (all blocks): R16 enc_half body for (b,h,half) -> enc_g
//  grid.sync()
//  phase B (blocks <128): R16 dec_attn body for (b,h)     -> xnp_g
//  grid.sync()
//  phase C (all blocks): stream out0 (nt); blocks 0..15 also fc1/fc2 + out1
// ---------------------------------------------------------------------------
__global__ __launch_bounds__(512) void mega(
    const float* __restrict__ xt, const float* __restrict__ enc_w,
    const float* __restrict__ enc_b, const float* __restrict__ weights,
    const float* __restrict__ dec_w, const float* __restrict__ dec_b,
    const float* __restrict__ mt, const float* __restrict__ fc1_w,
    const float* __restrict__ fc1_g, const float* __restrict__ fc1_b,
    const float* __restrict__ fc2_w, const float* __restrict__ fc2_g,
    const float* __restrict__ fc2_b, float* __restrict__ enc_g,
    float* __restrict__ xnp_g, float* __restrict__ out)
{
    __shared__ float Xs[C_][L_];          // 64 KB
    __shared__ float qkv_s[96][68];       // 26 KB  rows 0..31 q, 32..63 k, 64..95 v
    __shared__ float P[32][68];           // 8.7 KB
    __shared__ float wts[HC_][24];        // 3 KB
    __shared__ float qvs[HC_];
    __shared__ float aw[L_];
    __shared__ float fcb[2][C_];          // 2 KB (fc xs / y1)
    __shared__ float y2s[4];
    const int t   = threadIdx.x;          // 0..511
    const int bid = blockIdx.x;           // 0..255

    // ======================= phase A: encoder (R16 body) ===================
    {
        const int b    = bid >> 4;
        const int h    = (bid >> 1) & 7;
        const int half = bid & 1;
        const float* xtb = xt + (size_t)b * (C_ * L_);

        #pragma unroll
        for (int i = 0; i < 8; ++i) {
            int q = t + i * 512;
            int c = q >> 4, l4 = (q & 15) * 4;
            *reinterpret_cast<float4*>(&Xs[c][l4]) =
                *reinterpret_cast<const float4*>(&xtb[q * 4]);
        }
        #pragma unroll
        for (int idx = t; idx < HC_ * 24; idx += 512)
            wts[idx / 24][idx % 24] = weights[(h * HC_) * 24 + idx];
        __syncthreads();

        // qkv GEMM: all threads k+v rows; threads<256 q rows (this half)
        {
            const int kvr  = t >> 4;
            const int kvc4 = (t & 15) * 4;
            const int qr   = t >> 3;
            const int qc4  = half * 32 + (t & 7) * 4;
            const float* wk = enc_w + (size_t)(C_ + h * HC_ + kvr) * C_;
            const float* wv = enc_w + (size_t)(2 * C_ + h * HC_ + kvr) * C_;
            const float* wq = enc_w + (size_t)(h * HC_ + (qr & 31)) * C_;
            float4 acck = {}, accv = {}, accq = {};
            #pragma unroll 2
            for (int c0 = 0; c0 < C_; c0 += 4) {
                float4 xk0 = *reinterpret_cast<const float4*>(&Xs[c0 + 0][kvc4]);
                float4 xk1 = *reinterpret_cast<const float4*>(&Xs[c0 + 1][kvc4]);
                float4 xk2 = *reinterpret_cast<const float4*>(&Xs[c0 + 2][kvc4]);
                float4 xk3 = *reinterpret_cast<const float4*>(&Xs[c0 + 3][kvc4]);
                float4 wk4 = *reinterpret_cast<const float4*>(&wk[c0]);
                float4 wv4 = *reinterpret_cast<const float4*>(&wv[c0]);
                acck.x += wk4.x * xk0.x + wk4.y * xk1.x + wk4.z * xk2.x + wk4.w * xk3.x;
                acck.y += wk4.x * xk0.y + wk4.y * xk1.y + wk4.z * xk2.y + wk4.w * xk3.y;
                acck.z += wk4.x * xk0.z + wk4.y * xk1.z + wk4.z * xk2.z + wk4.w * xk3.z;
                acck.w += wk4.x * xk0.w + wk4.y * xk1.w + wk4.z * xk2.w + wk4.w * xk3.w;
                accv.x += wv4.x * xk0.x + wv4.y * xk1.x + wv4.z * xk2.x + wv4.w * xk3.x;
                accv.y += wv4.x * xk0.y + wv4.y * xk1.y + wv4.z * xk2.y + wv4.w * xk3.y;
                accv.z += wv4.x * xk0.z + wv4.y * xk1.z + wv4.z * xk2.z + wv4.w * xk3.z;
                accv.w += wv4.x * xk0.w + wv4.y * xk1.w + wv4.z * xk2.w + wv4.w * xk3.w;
                if (t < 256) {
                    float4 xq0 = *reinterpret_cast<const float4*>(&Xs[c0 + 0][qc4]);
                    float4 xq1 = *reinterpret_cast<const float4*>(&Xs[c0 + 1][qc4]);
                    float4 xq2 = *reinterpret_cast<const float4*>(&Xs[c0 + 2][qc4]);
                    float4 xq3 = *reinterpret_cast<const float4*>(&Xs[c0 + 3][qc4]);
                    float4 wq4 = *reinterpret_cast<const float4*>(&wq[c0]);
                    accq.x += wq4.x * xq0.x + wq4.y * xq1.x + wq4.z * xq2.x + wq4.w * xq3.x;
                    accq.y += wq4.x * xq0.y + wq4.y * xq1.y + wq4.z * xq2.y + wq4.w * xq3.y;
                    accq.z += wq4.x * xq0.z + wq4.y * xq1.z + wq4.z * xq2.z + wq4.w * xq3.z;
                    accq.w += wq4.x * xq0.w + wq4.y * xq1.w + wq4.z * xq2.w + wq4.w * xq3.w;
                }
            }
            float bk = enc_b[C_ + h * HC_ + kvr];
            float bv = enc_b[2 * C_ + h * HC_ + kvr];
            acck.x += bk; acck.y += bk; acck.z += bk; acck.w += bk;
            accv.x += bv; accv.y += bv; accv.z += bv; accv.w += bv;
            *reinterpret_cast<float4*>(&qkv_s[32 + kvr][kvc4]) = acck;
            *reinterpret_cast<float4*>(&qkv_s[64 + kvr][kvc4]) = accv;
            if (t < 256) {
                float bq = enc_b[h * HC_ + qr];
                accq.x += bq; accq.y += bq; accq.z += bq; accq.w += bq;
                *reinterpret_cast<float4*>(&qkv_s[qr][qc4]) = accq;
            }
        }
        __syncthreads();

        // scores
        {
            const int l = t >> 4;
            const int lp0 = (t & 15) * 4;
            const int qcol = half * 32 + l;
            float4 a4 = {0.f, 0.f, 0.f, 0.f};
            #pragma unroll
            for (int cc = 0; cc < HC_; ++cc) {
                float qv_ = qkv_s[cc][qcol];
                float4 k4 = *reinterpret_cast<const float4*>(&qkv_s[32 + cc][lp0]);
                a4.x += qv_ * k4.x; a4.y += qv_ * k4.y;
                a4.z += qv_ * k4.z; a4.w += qv_ * k4.w;
            }
            a4.x *= SQRT32F; a4.y *= SQRT32F; a4.z *= SQRT32F; a4.w *= SQRT32F;
            *reinterpret_cast<float4*>(&P[l][lp0]) = a4;
        }
        __syncthreads();

        // softmax: 16 threads/row
        {
            int l = t >> 4, p0 = (t & 15) * 4;
            float m = -1e30f;
            #pragma unroll
            for (int j = 0; j < 4; ++j) m = fmaxf(m, P[l][p0 + j]);
            m = fmaxf(m, __shfl_xor(m, 1));
            m = fmaxf(m, __shfl_xor(m, 2));
            m = fmaxf(m, __shfl_xor(m, 4));
            m = fmaxf(m, __shfl_xor(m, 8));
            float sum = 0.f;
            #pragma unroll
            for (int j = 0; j < 4; ++j) {
                float e = __expf(P[l][p0 + j] - m);
                P[l][p0 + j] = e;
                sum += e;
            }
            sum += __shfl_xor(sum, 1);
            sum += __shfl_xor(sum, 2);
            sum += __shfl_xor(sum, 4);
            sum += __shfl_xor(sum, 8);
            float inv = 1.0f / sum;
            #pragma unroll
            for (int j = 0; j < 4; ++j) P[l][p0 + j] *= inv;
        }
        __syncthreads();

        // PV + Fourier recurrence + residual -> enc_g
        {
            const int l0 = (t & 15) * 2;
            const int cc = t >> 4;
            float a0 = 0.f, a1 = 0.f;
            #pragma unroll
            for (int sq = 0; sq < 16; ++sq) {
                float4 p0v = *reinterpret_cast<const float4*>(&P[l0 + 0][sq * 4]);
                float4 p1v = *reinterpret_cast<const float4*>(&P[l0 + 1][sq * 4]);
                float4 v4  = *reinterpret_cast<const float4*>(&qkv_s[64 + cc][sq * 4]);
                a0 += p0v.x * v4.x + p0v.y * v4.y + p0v.z * v4.z + p0v.w * v4.w;
                a1 += p1v.x * v4.x + p1v.y * v4.y + p1v.z * v4.z + p1v.w * v4.w;
            }
            const float* wrf = wts[cc];
            const int c  = h * HC_ + cc;
            const int lg = half * 32 + l0;
            float av[2] = {a0, a1};
            float vv[2];
            #pragma unroll
            for (int i = 0; i < 2; ++i) {
                float val = Xs[c][lg + i] + wrf[M_];
                float base = av[i] * (PI_F / (float)M_);
                float s1, c1;
                __sincosf(base, &s1, &c1);
                float sm = 0.f, cm = 1.f;
                #pragma unroll
                for (int m = 1; m < M_; ++m) {
                    float sp = sm * c1 + cm * s1;
                    float cp = cm * c1 - sm * s1;
                    sm = sp; cm = cp;
                    val += wrf[m] * sm + wrf[M_ + m] * cm;
                }
                vv[i] = val;
            }
            *reinterpret_cast<float2*>(&enc_g[((size_t)b * C_ + c) * L_ + lg]) =
                make_float2(vv[0], vv[1]);
        }
    }

    cg::this_grid().sync();

    // ======================= phase B: decoder (blocks < 128) ===============
    if (bid < 128) {
        const int b = bid >> 3;
        const int h = bid & 7;
        const float* ench = enc_g + ((size_t)b * C_ + h * HC_) * L_;

        if (t < 64) {      // qv: 2 threads/row
            int r = t >> 1, part = t & 1;
            const float* wr = dec_w + (size_t)(h * HC_ + r) * C_ + part * 128;
            const float* mp = mt + part * 128;
            float s = 0.f;
            #pragma unroll
            for (int j = 0; j < 32; ++j) {
                float4 w4 = *reinterpret_cast<const float4*>(&wr[j * 4]);
                float4 m4 = *reinterpret_cast<const float4*>(&mp[j * 4]);
                s += w4.x * m4.x + w4.y * m4.y + w4.z * m4.z + w4.w * m4.w;
            }
            s += __shfl_xor(s, 1);
            if (part == 0) qvs[r] = s + dec_b[h * HC_ + r];
        }
        __syncthreads();
        if (t < 64) {
            int l = t;
            float s = 0.f;
            #pragma unroll
            for (int cc = 0; cc < HC_; ++cc)
                s += qvs[cc] * ench[cc * L_ + l];
            s *= SQRT32F;
            float m = s;
            #pragma unroll
            for (int off = 32; off >= 1; off >>= 1) m = fmaxf(m, __shfl_xor(m, off));
            float e = __expf(s - m);
            float sum = e;
            #pragma unroll
            for (int off = 32; off >= 1; off >>= 1) sum += __shfl_xor(sum, off);
            aw[l] = e / sum;
        }
        __syncthreads();
        if (t < HC_) {
            const float* vrow = ench + t * L_;
            float a = 0.f;
            #pragma unroll
            for (int k4 = 0; k4 < L_; k4 += 4) {
                float4 a4 = *reinterpret_cast<const float4*>(&aw[k4]);
                float4 v4 = *reinterpret_cast<const float4*>(&vrow[k4]);
                a += a4.x * v4.x + a4.y * v4.y + a4.z * v4.z + a4.w * v4.w;
            }
            int c = h * HC_ + t;
            xnp_g[b * C_ + c] = a + mt[c];
        }
    }

    cg::this_grid().sync();

    // ======================= phase C: output writes ========================
    if (bid >= 16) {
        // 17 out0 rows each: rows (bid-16)*17 .. +16  (covers 0..4079)
        int r0 = (bid - 16) * 17;
        #pragma unroll
        for (int i = 0; i < 17; ++i) {
            int row = r0 + i;
            float v = xnp_g[row];
            v4f V = {v, v, v, v};
            v4f* rp = reinterpret_cast<v4f*>(out + (size_t)row * N_);
            #pragma unroll
            for (int j = 0; j < 4; ++j)
                __builtin_nontemporal_store(V, &rp[t + j * 512]);
        }
    } else {
        // blocks 0..15: out0 row 4080+bid, then fc1/fc2 + out1 for batch bid
        {
            int row = 4080 + bid;
            float v = xnp_g[row];
            v4f V = {v, v, v, v};
            v4f* rp = reinterpret_cast<v4f*>(out + (size_t)row * N_);
            #pragma unroll
            for (int j = 0; j < 4; ++j)
                __builtin_nontemporal_store(V, &rp[t + j * 512]);
        }
        const int b = bid;
        if (t < C_) fcb[0][t] = xnp_g[b * C_ + t];
        __syncthreads();
        if (t < C_) {
            const float* wrow = fc1_w + (size_t)t * C_;
            float s = 0.f;
            #pragma unroll 8
            for (int c4 = 0; c4 < C_; c4 += 4) {
                float4 w4 = *reinterpret_cast<const float4*>(&wrow[c4]);
                float4 x4 = *reinterpret_cast<const float4*>(&fcb[0][c4]);
                s += w4.x * x4.x + w4.y * x4.y + w4.z * x4.z + w4.w * x4.w;
            }
            float y = fc1_g[t] * s * BN_INV + fc1_b[t];
            fcb[1][t] = (y >= 0.f) ? y : 0.2f * y;
        }
        __syncthreads();
        if (t < 3) {
            const float* wrow = fc2_w + t * C_;
            float s = 0.f;
            #pragma unroll 8
            for (int c4 = 0; c4 < C_; c4 += 4) {
                float4 w4 = *reinterpret_cast<const float4*>(&wrow[c4]);
                float4 x4 = *reinterpret_cast<const float4*>(&fcb[1][c4]);
                s += w4.x * x4.x + w4.y * x4.y + w4.z * x4.z + w4.w * x4.w;
            }
            float y = fc2_g[t] * s * BN_INV + fc2_b[t];
            y2s[t] = (y >= 0.f) ? y : 0.2f * y;
        }
        __syncthreads();
        float v0 = y2s[0], v1 = y2s[1], v2 = y2s[2];
        v4f pat0 = {v0, v1, v2, v0};
        v4f pat1 = {v1, v2, v0, v1};
        v4f pat2 = {v2, v0, v1, v2};
        // f = t + i*512; 512 % 3 == 2 -> f%3 == (t + 2i) % 3; shift cycle [0,2,1]
        int r = t % 3;
        v4f pA = (r == 0) ? pat0 : (r == 1) ? pat1 : pat2;
        v4f pB = (r == 0) ? pat2 : (r == 1) ? pat0 : pat1;
        v4f pC = (r == 0) ? pat1 : (r == 1) ? pat2 : pat0;
        v4f* o1 = reinterpret_cast<v4f*>(
            out + (size_t)B_ * C_ * N_ + (size_t)b * (N_ * 3));
        #pragma unroll
        for (int i = 0; i < 12; i += 3) {    // 6144 float4 = 8192*3 f32
            __builtin_nontemporal_store(pA, &o1[t + (i + 0) * 512]);
            __builtin_nontemporal_store(pB, &o1[t + (i + 1) * 512]);
            __builtin_nontemporal_store(pC, &o1[t + (i + 2) * 512]);
        }
    }
}

// ---------------------------------------------------------------------------
extern "C" void kernel_launch(void* const* d_in, const int* in_sizes, int n_in,
                              void* d_out, int out_size, void* d_ws, size_t ws_size,
                              hipStream_t stream) {
    const float* xt      = (const float*)d_in[0];
    // d_in[1] = xn : unused (length N is compile-time)
    const float* weights = (const float*)d_in[2];
    const float* mt      = (const float*)d_in[3];
    const float* enc_w   = (const float*)d_in[4];
    const float* enc_b   = (const float*)d_in[5];
    const float* dec_w   = (const float*)d_in[6];
    const float* dec_b   = (const float*)d_in[7];
    const float* fc1_w   = (const float*)d_in[8];
    const float* fc1_g   = (const float*)d_in[9];
    const float* fc1_b   = (const float*)d_in[10];
    const float* fc2_w   = (const float*)d_in[11];
    const float* fc2_g   = (const float*)d_in[12];
    const float* fc2_b   = (const float*)d_in[13];

    float* ws    = (float*)d_ws;
    float* enc_g = ws;                // 262144 floats (1 MB)
    float* xnp_g = ws + 262144;       // 4096 floats
    float* out   = (float*)d_out;

    void* args[] = {
        (void*)&xt, (void*)&enc_w, (void*)&enc_b, (void*)&weights,
        (void*)&dec_w, (void*)&dec_b, (void*)&mt, (void*)&fc1_w,
        (void*)&fc1_g, (void*)&fc1_b, (void*)&fc2_w, (void*)&fc2_g,
        (void*)&fc2_b, (void*)&enc_g, (void*)&xnp_g, (void*)&out
    };
    hipLaunchCooperativeKernel((void*)mega, dim3(256), dim3(512),
                               args, 0, stream);
}

// Round 18
// 56.907 us; speedup vs baseline: 2.0073x; 2.0073x over previous
//
#include <hip/hip_runtime.h>
#include <hip/hip_bf16.h>
#include <math.h>

// Problem constants
#define B_    16
#define C_    256
#define L_    64
#define N_    8192
#define HEAD_ 8
#define HC_   32        // C/HEAD
#define M_    12

#define SQRT32F 5.656854249492380f
#define PI_F    3.14159265358979323846f
#define BN_INV  0.99999500003749969f     // 1/sqrt(1+1e-5)

typedef float v4f __attribute__((ext_vector_type(4)));

// ---------------------------------------------------------------------------
// Kernel 1: block 0 -> qv = dec_w @ mask_token + dec_b (R7-proven form);
// blocks 1..256 -> encoder attention per (b,h,half) (R16-proven body).
// ---------------------------------------------------------------------------
__global__ __launch_bounds__(512) void enc_qv(
    const float* __restrict__ xt, const float* __restrict__ enc_w,
    const float* __restrict__ enc_b, const float* __restrict__ weights,
    const float* __restrict__ dec_w, const float* __restrict__ dec_b,
    const float* __restrict__ mt, float* __restrict__ enc_g,
    float* __restrict__ qv_g)
{
    __shared__ float Xs[C_][L_];          // 64 KB
    __shared__ float qkv_s[96][68];       // 26 KB
    __shared__ float P[32][68];           // 8.7 KB
    __shared__ float wts[HC_][24];        // 3 KB
    __shared__ float mts[C_];             // 1 KB (qv block)
    const int t = threadIdx.x;            // 0..511

    if (blockIdx.x == 0) {
        if (t < C_) mts[t] = mt[t];
        __syncthreads();
        if (t < C_) {
            const float* wrow = dec_w + (size_t)t * C_;
            float s = 0.f;
            #pragma unroll 8
            for (int c4 = 0; c4 < C_; c4 += 4) {
                float4 w4 = *reinterpret_cast<const float4*>(&wrow[c4]);
                float4 m4 = *reinterpret_cast<const float4*>(&mts[c4]);
                s += w4.x * m4.x + w4.y * m4.y + w4.z * m4.z + w4.w * m4.w;
            }
            qv_g[t] = s + dec_b[t];
        }
        return;
    }

    const int bid  = blockIdx.x - 1;      // 0..255
    const int b    = bid >> 4;
    const int h    = (bid >> 1) & 7;
    const int half = bid & 1;
    const float* xtb = xt + (size_t)b * (C_ * L_);

    // ---- stage xt[b] + weights h-slice ----
    #pragma unroll
    for (int i = 0; i < 8; ++i) {
        int q = t + i * 512;
        int c = q >> 4, l4 = (q & 15) * 4;
        *reinterpret_cast<float4*>(&Xs[c][l4]) =
            *reinterpret_cast<const float4*>(&xtb[q * 4]);
    }
    #pragma unroll
    for (int idx = t; idx < HC_ * 24; idx += 512)
        wts[idx / 24][idx % 24] = weights[(h * HC_) * 24 + idx];
    __syncthreads();

    // ---- qkv GEMM ----
    {
        const int kvr  = t >> 4;
        const int kvc4 = (t & 15) * 4;
        const int qr   = t >> 3;
        const int qc4  = half * 32 + (t & 7) * 4;
        const float* wk = enc_w + (size_t)(C_ + h * HC_ + kvr) * C_;
        const float* wv = enc_w + (size_t)(2 * C_ + h * HC_ + kvr) * C_;
        const float* wq = enc_w + (size_t)(h * HC_ + (qr & 31)) * C_;
        float4 acck = {}, accv = {}, accq = {};
        #pragma unroll 2
        for (int c0 = 0; c0 < C_; c0 += 4) {
            float4 xk0 = *reinterpret_cast<const float4*>(&Xs[c0 + 0][kvc4]);
            float4 xk1 = *reinterpret_cast<const float4*>(&Xs[c0 + 1][kvc4]);
            float4 xk2 = *reinterpret_cast<const float4*>(&Xs[c0 + 2][kvc4]);
            float4 xk3 = *reinterpret_cast<const float4*>(&Xs[c0 + 3][kvc4]);
            float4 wk4 = *reinterpret_cast<const float4*>(&wk[c0]);
            float4 wv4 = *reinterpret_cast<const float4*>(&wv[c0]);
            acck.x += wk4.x * xk0.x + wk4.y * xk1.x + wk4.z * xk2.x + wk4.w * xk3.x;
            acck.y += wk4.x * xk0.y + wk4.y * xk1.y + wk4.z * xk2.y + wk4.w * xk3.y;
            acck.z += wk4.x * xk0.z + wk4.y * xk1.z + wk4.z * xk2.z + wk4.w * xk3.z;
            acck.w += wk4.x * xk0.w + wk4.y * xk1.w + wk4.z * xk2.w + wk4.w * xk3.w;
            accv.x += wv4.x * xk0.x + wv4.y * xk1.x + wv4.z * xk2.x + wv4.w * xk3.x;
            accv.y += wv4.x * xk0.y + wv4.y * xk1.y + wv4.z * xk2.y + wv4.w * xk3.y;
            accv.z += wv4.x * xk0.z + wv4.y * xk1.z + wv4.z * xk2.z + wv4.w * xk3.z;
            accv.w += wv4.x * xk0.w + wv4.y * xk1.w + wv4.z * xk2.w + wv4.w * xk3.w;
            if (t < 256) {
                float4 xq0 = *reinterpret_cast<const float4*>(&Xs[c0 + 0][qc4]);
                float4 xq1 = *reinterpret_cast<const float4*>(&Xs[c0 + 1][qc4]);
                float4 xq2 = *reinterpret_cast<const float4*>(&Xs[c0 + 2][qc4]);
                float4 xq3 = *reinterpret_cast<const float4*>(&Xs[c0 + 3][qc4]);
                float4 wq4 = *reinterpret_cast<const float4*>(&wq[c0]);
                accq.x += wq4.x * xq0.x + wq4.y * xq1.x + wq4.z * xq2.x + wq4.w * xq3.x;
                accq.y += wq4.x * xq0.y + wq4.y * xq1.y + wq4.z * xq2.y + wq4.w * xq3.y;
                accq.z += wq4.x * xq0.z + wq4.y * xq1.z + wq4.z * xq2.z + wq4.w * xq3.z;
                accq.w += wq4.x * xq0.w + wq4.y * xq1.w + wq4.z * xq2.w + wq4.w * xq3.w;
            }
        }
        float bk = enc_b[C_ + h * HC_ + kvr];
        float bv = enc_b[2 * C_ + h * HC_ + kvr];
        acck.x += bk; acck.y += bk; acck.z += bk; acck.w += bk;
        accv.x += bv; accv.y += bv; accv.z += bv; accv.w += bv;
        *reinterpret_cast<float4*>(&qkv_s[32 + kvr][kvc4]) = acck;
        *reinterpret_cast<float4*>(&qkv_s[64 + kvr][kvc4]) = accv;
        if (t < 256) {
            float bq = enc_b[h * HC_ + (t >> 3)];
            accq.x += bq; accq.y += bq; accq.z += bq; accq.w += bq;
            *reinterpret_cast<float4*>(&qkv_s[t >> 3][qc4]) = accq;
        }
    }
    __syncthreads();

    // ---- scores ----
    {
        const int l = t >> 4;
        const int lp0 = (t & 15) * 4;
        const int qcol = half * 32 + l;
        float4 a4 = {0.f, 0.f, 0.f, 0.f};
        #pragma unroll
        for (int cc = 0; cc < HC_; ++cc) {
            float qv_ = qkv_s[cc][qcol];
            float4 k4 = *reinterpret_cast<const float4*>(&qkv_s[32 + cc][lp0]);
            a4.x += qv_ * k4.x; a4.y += qv_ * k4.y;
            a4.z += qv_ * k4.z; a4.w += qv_ * k4.w;
        }
        a4.x *= SQRT32F; a4.y *= SQRT32F; a4.z *= SQRT32F; a4.w *= SQRT32F;
        *reinterpret_cast<float4*>(&P[l][lp0]) = a4;
    }
    __syncthreads();

    // ---- softmax: 16 threads/row ----
    {
        int l = t >> 4, p0 = (t & 15) * 4;
        float m = -1e30f;
        #pragma unroll
        for (int j = 0; j < 4; ++j) m = fmaxf(m, P[l][p0 + j]);
        m = fmaxf(m, __shfl_xor(m, 1));
        m = fmaxf(m, __shfl_xor(m, 2));
        m = fmaxf(m, __shfl_xor(m, 4));
        m = fmaxf(m, __shfl_xor(m, 8));
        float sum = 0.f;
        #pragma unroll
        for (int j = 0; j < 4; ++j) {
            float e = __expf(P[l][p0 + j] - m);
            P[l][p0 + j] = e;
            sum += e;
        }
        sum += __shfl_xor(sum, 1);
        sum += __shfl_xor(sum, 2);
        sum += __shfl_xor(sum, 4);
        sum += __shfl_xor(sum, 8);
        float inv = 1.0f / sum;
        #pragma unroll
        for (int j = 0; j < 4; ++j) P[l][p0 + j] *= inv;
    }
    __syncthreads();

    // ---- PV + Fourier recurrence + residual -> enc_g ----
    {
        const int l0 = (t & 15) * 2;
        const int cc = t >> 4;
        float a0 = 0.f, a1 = 0.f;
        #pragma unroll
        for (int sq = 0; sq < 16; ++sq) {
            float4 p0v = *reinterpret_cast<const float4*>(&P[l0 + 0][sq * 4]);
            float4 p1v = *reinterpret_cast<const float4*>(&P[l0 + 1][sq * 4]);
            float4 v4  = *reinterpret_cast<const float4*>(&qkv_s[64 + cc][sq * 4]);
            a0 += p0v.x * v4.x + p0v.y * v4.y + p0v.z * v4.z + p0v.w * v4.w;
            a1 += p1v.x * v4.x + p1v.y * v4.y + p1v.z * v4.z + p1v.w * v4.w;
        }
        const float* wrf = wts[cc];
        const int c  = h * HC_ + cc;
        const int lg = half * 32 + l0;
        float av[2] = {a0, a1};
        float vv[2];
        #pragma unroll
        for (int i = 0; i < 2; ++i) {
            float val = Xs[c][lg + i] + wrf[M_];   // m=0: sin=0, cos=1
            float base = av[i] * (PI_F / (float)M_);
            float s1, c1;
            __sincosf(base, &s1, &c1);
            float sm = 0.f, cm = 1.f;
            #pragma unroll
            for (int m = 1; m < M_; ++m) {
                float sp = sm * c1 + cm * s1;
                float cp = cm * c1 - sm * s1;
                sm = sp; cm = cp;
                val += wrf[m] * sm + wrf[M_ + m] * cm;
            }
            vv[i] = val;
        }
        *reinterpret_cast<float2*>(&enc_g[((size_t)b * C_ + c) * L_ + lg]) =
            make_float2(vv[0], vv[1]);
    }
}

// ---------------------------------------------------------------------------
// Kernel 2: decode-inline broadcast.
//   blocks 16..4111: row (b,c) -> compute xnp[b,c] from enc_g+qv, splat 32KB
//   blocks 0..15:    full xnp[b,:] -> fc1/fc2 -> out1 splat
// ---------------------------------------------------------------------------
__global__ __launch_bounds__(256) void dec_bcast(
    const float* __restrict__ enc_g, const float* __restrict__ qv_g,
    const float* __restrict__ mt, const float* __restrict__ fc1_w,
    const float* __restrict__ fc1_g, const float* __restrict__ fc1_b,
    const float* __restrict__ fc2_w, const float* __restrict__ fc2_g,
    const float* __restrict__ fc2_b, float* __restrict__ out)
{
    __shared__ float sc4[4][64];      // score partials (splat path)
    __shared__ float aw[L_];
    __shared__ float xv;
    __shared__ float scf[8][68];      // per-head scores (fc path)
    __shared__ float xnp[C_];
    __shared__ float y1[C_];
    __shared__ float y2s[4];
    const int t = threadIdx.x;
    const int blk = blockIdx.x;

    if (blk >= 16) {
        // ---- splat block: row (b,c) ----
        const int row = blk - 16;
        const int b = row >> 8, c = row & 255, h = c >> 5;
        const float* encH = enc_g + ((size_t)b * C_ + h * HC_) * L_;
        // scores: 4 waves x 64 keys, 8-cc partial each (coalesced over k)
        {
            int part = t >> 6, k = t & 63;
            float s = 0.f;
            #pragma unroll
            for (int j = 0; j < 8; ++j) {
                int cc = part * 8 + j;
                s += qv_g[h * HC_ + cc] * encH[cc * L_ + k];
            }
            sc4[part][k] = s;
        }
        __syncthreads();
        if (t < 64) {
            float s = (sc4[0][t] + sc4[1][t] + sc4[2][t] + sc4[3][t]) * SQRT32F;
            float m = s;
            #pragma unroll
            for (int off = 32; off >= 1; off >>= 1) m = fmaxf(m, __shfl_xor(m, off));
            float e = __expf(s - m);
            float sum = e;
            #pragma unroll
            for (int off = 32; off >= 1; off >>= 1) sum += __shfl_xor(sum, off);
            aw[t] = e / sum;
        }
        __syncthreads();
        if (t < 64) {
            float p = aw[t] * enc_g[((size_t)b * C_ + c) * L_ + t];
            #pragma unroll
            for (int off = 32; off >= 1; off >>= 1) p += __shfl_xor(p, off);
            if (t == 0) xv = p + mt[c];
        }
        __syncthreads();
        float v = xv;
        v4f V = {v, v, v, v};
        v4f* rp = reinterpret_cast<v4f*>(out + (size_t)row * N_);
        #pragma unroll
        for (int i = 0; i < 8; ++i)
            __builtin_nontemporal_store(V, &rp[t + i * 256]);   // 2048 x 16B
    } else {
        // ---- fc block: batch b ----
        const int b = blk;
        // scores for all 8 heads (512 jobs, 2/thread)
        #pragma unroll
        for (int jj = 0; jj < 2; ++jj) {
            int job = t + jj * 256;           // 0..511
            int h = job >> 6, k = job & 63;
            const float* encH = enc_g + ((size_t)b * C_ + h * HC_) * L_;
            float s = 0.f;
            #pragma unroll
            for (int cc = 0; cc < HC_; ++cc)
                s += qv_g[h * HC_ + cc] * encH[cc * L_ + k];
            scf[h][k] = s * SQRT32F;
        }
        __syncthreads();
        if (t < 8) {          // serial softmax per head
            float m = -1e30f;
            for (int j = 0; j < L_; ++j) m = fmaxf(m, scf[t][j]);
            float sum = 0.f;
            for (int j = 0; j < L_; ++j) {
                float e = __expf(scf[t][j] - m);
                scf[t][j] = e;
                sum += e;
            }
            float inv = 1.0f / sum;
            for (int j = 0; j < L_; ++j) scf[t][j] *= inv;
        }
        __syncthreads();
        // xnp[c], c = t
        {
            int h = t >> 5;
            const float* er = enc_g + ((size_t)b * C_ + t) * L_;
            float a = 0.f;
            #pragma unroll
            for (int k4 = 0; k4 < L_; k4 += 4) {
                float4 a4 = *reinterpret_cast<const float4*>(&scf[h][k4]);
                float4 v4 = *reinterpret_cast<const float4*>(&er[k4]);
                a += a4.x * v4.x + a4.y * v4.y + a4.z * v4.z + a4.w * v4.w;
            }
            xnp[t] = a + mt[t];
        }
        __syncthreads();
        // fc1 + BN + LeakyReLU
        {
            const float* wrow = fc1_w + (size_t)t * C_;
            float s = 0.f;
            #pragma unroll 8
            for (int c4 = 0; c4 < C_; c4 += 4) {
                float4 w4 = *reinterpret_cast<const float4*>(&wrow[c4]);
                float4 x4 = *reinterpret_cast<const float4*>(&xnp[c4]);
                s += w4.x * x4.x + w4.y * x4.y + w4.z * x4.z + w4.w * x4.w;
            }
            float y = fc1_g[t] * s * BN_INV + fc1_b[t];
            y1[t] = (y >= 0.f) ? y : 0.2f * y;
        }
        __syncthreads();
        if (t < 3) {
            const float* wrow = fc2_w + t * C_;
            float s = 0.f;
            #pragma unroll 8
            for (int c4 = 0; c4 < C_; c4 += 4) {
                float4 w4 = *reinterpret_cast<const float4*>(&wrow[c4]);
                float4 x4 = *reinterpret_cast<const float4*>(&y1[c4]);
                s += w4.x * x4.x + w4.y * x4.y + w4.z * x4.z + w4.w * x4.w;
            }
            float y = fc2_g[t] * s * BN_INV + fc2_b[t];
            y2s[t] = (y >= 0.f) ? y : 0.2f * y;
        }
        __syncthreads();
        float v0 = y2s[0], v1 = y2s[1], v2 = y2s[2];
        v4f pat0 = {v0, v1, v2, v0};
        v4f pat1 = {v1, v2, v0, v1};
        v4f pat2 = {v2, v0, v1, v2};
        // f = t + i*256; 256 % 3 == 1 -> f%3 == (t + i) % 3
        int r = t % 3;
        v4f a = (r == 0) ? pat0 : (r == 1) ? pat1 : pat2;
        v4f bb = (r == 0) ? pat1 : (r == 1) ? pat2 : pat0;
        v4f cpat = (r == 0) ? pat2 : (r == 1) ? pat0 : pat1;
        v4f* o1 = reinterpret_cast<v4f*>(
            out + (size_t)B_ * C_ * N_ + (size_t)b * (N_ * 3));
        #pragma unroll
        for (int i = 0; i < 24; i += 3) {    // 6144 float4 = 8192*3 f32
            __builtin_nontemporal_store(a,    &o1[t + (i + 0) * 256]);
            __builtin_nontemporal_store(bb,   &o1[t + (i + 1) * 256]);
            __builtin_nontemporal_store(cpat, &o1[t + (i + 2) * 256]);
        }
    }
}

// ---------------------------------------------------------------------------
extern "C" void kernel_launch(void* const* d_in, const int* in_sizes, int n_in,
                              void* d_out, int out_size, void* d_ws, size_t ws_size,
                              hipStream_t stream) {
    const float* xt      = (const float*)d_in[0];
    // d_in[1] = xn : unused (length N is compile-time)
    const float* weights = (const float*)d_in[2];
    const float* mt      = (const float*)d_in[3];
    const float* enc_w   = (const float*)d_in[4];
    const float* enc_b   = (const float*)d_in[5];
    const float* dec_w   = (const float*)d_in[6];
    const float* dec_b   = (const float*)d_in[7];
    const float* fc1_w   = (const float*)d_in[8];
    const float* fc1_g   = (const float*)d_in[9];
    const float* fc1_b   = (const float*)d_in[10];
    const float* fc2_w   = (const float*)d_in[11];
    const float* fc2_g   = (const float*)d_in[12];
    const float* fc2_b   = (const float*)d_in[13];

    float* ws    = (float*)d_ws;
    float* enc_g = ws;                // 262144 floats (1 MB)
    float* qv_g  = ws + 262144;       // 256 floats
    float* out   = (float*)d_out;

    enc_qv<<<257, 512, 0, stream>>>(xt, enc_w, enc_b, weights,
                                    dec_w, dec_b, mt, enc_g, qv_g);
    dec_bcast<<<4112, 256, 0, stream>>>(enc_g, qv_g, mt,
                                        fc1_w, fc1_g, fc1_b,
                                        fc2_w, fc2_g, fc2_b, out);
}